// Round 1
// baseline (10798.089 us; speedup 1.0000x reference)
//
#include <hip/hip_runtime.h>
#include <stdint.h>

#define BATCH 128
#define TSTEPS 250
#define NIN 700
#define NHID 1024
#define NBR 4
#define NOUT 20
#define KDIM 1724          // NIN + NHID
#define NR 4096            // NHID * NBR
#define VTH 0.5f

// ---------------- setup kernels ----------------

__global__ void setup_small(const float* __restrict__ tau_m1, const float* __restrict__ tau_n,
                            const float* __restrict__ tau_m2, const float* __restrict__ W2,
                            float* __restrict__ alpha1, float* __restrict__ beta,
                            float* __restrict__ alpha2, float* __restrict__ W2T) {
    int i = blockIdx.x * blockDim.x + threadIdx.x;
    if (i < NHID)  alpha1[i] = 1.f / (1.f + expf(-tau_m1[i]));
    if (i < NR)    beta[i]   = 1.f / (1.f + expf(-tau_n[i]));   // tau_n row-major [HID][BR] == flat r
    if (i < 32)    alpha2[i] = (i < NOUT) ? 1.f / (1.f + expf(-tau_m2[i])) : 0.f;
    if (i < NHID * 32) {                                        // W2T padded [1024][32]
        int j = i >> 5, o = i & 31;
        W2T[i] = (o < NOUT) ? W2[o * NHID + j] : 0.f;
    }
}

// W1xT[k][r] (k<700) and W1hTb[blk][n][16] masked transposes
__global__ void setup_weights(const float* __restrict__ W1, const int* __restrict__ mask,
                              float* __restrict__ W1xT, float* __restrict__ W1hTb) {
    const int total1 = NIN * NR;            // 2,867,200
    const int total2 = 256 * 16384;         // 4,194,304
    for (int i = blockIdx.x * blockDim.x + threadIdx.x; i < total1 + total2;
         i += gridDim.x * blockDim.x) {
        if (i < total1) {
            int k = i >> 12, r = i & 4095;
            size_t src = (size_t)r * KDIM + k;
            W1xT[i] = W1[src] * (float)mask[src];
        } else {
            int j = i - total1;
            int blk = j >> 14, rem = j & 16383;
            int n = rem >> 4, rl = rem & 15;
            int r = (blk << 4) + rl;
            size_t src = (size_t)r * KDIM + NIN + n;
            W1hTb[j] = W1[src] * (float)mask[src];
        }
    }
}

__global__ void init_state(const float* __restrict__ mem1_0, const float* __restrict__ mem2_0,
                           float* __restrict__ mem1, float* __restrict__ mem2,
                           float* __restrict__ spk2, float* __restrict__ d_inp,
                           uint32_t* __restrict__ spkg) {
    int i = blockIdx.x * blockDim.x + threadIdx.x;
    if (i < BATCH * NR) d_inp[i] = 0.f;
    if (i < BATCH * NHID) mem1[i] = mem1_0[i];
    if (i < BATCH * NOUT) { mem2[i] = mem2_0[i]; spk2[i] = 0.f; }
    if (i < 2 * BATCH * 64) spkg[i] = 0u;   // both spike-mask buffers
}

// ---------------- FFX GEMM: ffx[b*Tc+dt][r] = sum_k x[b][t0+dt][k]*W1xT[k][r] + b1[r] ----------------

#define GBM 128
#define GBN 128
#define GBK 16

__global__ __launch_bounds__(256) void ffx_gemm(const float* __restrict__ x,
                                                const float* __restrict__ W1xT,
                                                const float* __restrict__ b1,
                                                float* __restrict__ ffx, int t0, int Tc) {
    __shared__ float As[GBK][GBM];
    __shared__ float Bs[GBK][GBN];
    int bm = blockIdx.x, bn = blockIdx.y;
    int tid = threadIdx.x;
    int tn = tid & 15, tm = tid >> 4;

    float acc[8][8];
#pragma unroll
    for (int i = 0; i < 8; ++i)
#pragma unroll
        for (int j = 0; j < 8; ++j) acc[i][j] = 0.f;

    // A-load mapping: 2 threads per row
    int m_l = tid >> 1;
    int m_g = bm * GBM + m_l;
    int b_idx = m_g / Tc;
    int dt = m_g - b_idx * Tc;
    const float* xrow = x + ((size_t)b_idx * TSTEPS + t0 + dt) * NIN;
    int kh = (tid & 1) * 8;
    // B-load mapping
    int kb = tid >> 4;
    int nb = (tid & 15) * 8;

    for (int k0 = 0; k0 < NIN; k0 += GBK) {
        float av[8];
#pragma unroll
        for (int u = 0; u < 8; ++u) {
            int k = k0 + kh + u;
            av[u] = (k < NIN) ? xrow[k] : 0.f;
        }
#pragma unroll
        for (int u = 0; u < 8; ++u) As[kh + u][m_l] = av[u];

        bool kok = (k0 + kb) < NIN;
        const float* bp = W1xT + (size_t)(k0 + kb) * NR + bn * GBN + nb;
        float bv[8];
#pragma unroll
        for (int u = 0; u < 8; ++u) bv[u] = kok ? bp[u] : 0.f;
#pragma unroll
        for (int u = 0; u < 8; ++u) Bs[kb][nb + u] = bv[u];

        __syncthreads();
#pragma unroll
        for (int kk = 0; kk < GBK; ++kk) {
            float a[8], b[8];
#pragma unroll
            for (int u = 0; u < 8; ++u) a[u] = As[kk][tm * 8 + u];
#pragma unroll
            for (int u = 0; u < 8; ++u) b[u] = Bs[kk][tn * 8 + u];
#pragma unroll
            for (int i = 0; i < 8; ++i)
#pragma unroll
                for (int j = 0; j < 8; ++j) acc[i][j] += a[i] * b[j];
        }
        __syncthreads();
    }

    float bias[8];
#pragma unroll
    for (int j = 0; j < 8; ++j) bias[j] = b1[bn * GBN + tn * 8 + j];
#pragma unroll
    for (int i = 0; i < 8; ++i) {
        int row = bm * GBM + tm * 8 + i;
        float* cp = ffx + (size_t)row * NR + bn * GBN + tn * 8;
#pragma unroll
        for (int j = 0; j < 8; ++j) cp[j] = acc[i][j] + bias[j];
    }
}

// ---------------- per-timestep kernel ----------------
// grid 256 blocks x 512 threads. Block blk owns r-tile [blk*16, blk*16+16) = neurons [blk*4, blk*4+4).
// Blocks 0..7 additionally run layer-2 + log_softmax for step t-1 (16 batches each).
// Spike masks: spkg[buf][b][64 words]; byte g of batch b = 4 spike bits of neurons 4g..4g+3.

__global__ __launch_bounds__(512) void step_kernel(
    const float* __restrict__ alpha1, const float* __restrict__ beta,
    const float* __restrict__ alpha2, float* __restrict__ mem1, float* __restrict__ mem2,
    float* __restrict__ spk2, float* __restrict__ d_inp,
    const float* __restrict__ W1hTb, const float* __restrict__ W2T,
    const float* __restrict__ ffx, const float* __restrict__ b2,
    float* __restrict__ out, const uint32_t* __restrict__ spkg_prev,
    uint32_t* __restrict__ spkg_next, int t, int t_local, int Tc) {
    __shared__ float lds_W[NHID * 17];      // padded: bank-conflict-free column reads
    __shared__ uint32_t lds_mask[BATCH * 64];

    int blk = blockIdx.x;
    int tid = threadIdx.x;

    if (t < TSTEPS) {
        const float4* wsrc = (const float4*)(W1hTb + (size_t)blk * 16384);
        for (int i4 = tid; i4 < 4096; i4 += 512) {
            float4 v = wsrc[i4];
            int n = i4 >> 2, rb = (i4 & 3) * 4;
            lds_W[n * 17 + rb + 0] = v.x;
            lds_W[n * 17 + rb + 1] = v.y;
            lds_W[n * 17 + rb + 2] = v.z;
            lds_W[n * 17 + rb + 3] = v.w;
        }
    }
    for (int i = tid; i < BATCH * 64; i += 512) lds_mask[i] = spkg_prev[i];
    __syncthreads();

    // ---------- phase 1: recurrent accumulate + dendrite + mem1 + spike ----------
    if (t < TSTEPS) {
        int r_l = tid & 15;
        int bg = tid >> 4;          // 0..31, 4 batches each
        float acc[4];
#pragma unroll
        for (int i = 0; i < 4; ++i) {
            int b = bg * 4 + i;
            const uint32_t* mw = &lds_mask[b * 64];
            float a = 0.f;
            for (int w = 0; w < 64; ++w) {
                uint32_t bits = mw[w];
                while (bits) {
                    int p = __builtin_ctz(bits);
                    bits &= bits - 1;
                    int n = (w << 4) + ((p >> 3) << 2) + (p & 7);
                    a += lds_W[n * 17 + r_l];
                }
            }
            acc[i] = a;
        }

        int r_g = (blk << 4) + r_l;
        float beta_r = beta[r_g];
        int neuron = (blk << 2) + (r_l >> 2);
        float al = alpha1[neuron];
        int wv = blk >> 2;
        int bitbase = ((blk & 3) << 3) + (r_l >> 2);

#pragma unroll
        for (int i = 0; i < 4; ++i) {
            int b = bg * 4 + i;
            float ff = acc[i] + ffx[((size_t)b * Tc + t_local) * NR + r_g];
            size_t di_idx = (size_t)b * NR + r_g;
            float di = d_inp[di_idx];
            di = beta_r * di + (1.f - beta_r) * ff;
            d_inp[di_idx] = di;
            float ls = di + __shfl_xor(di, 1);
            ls += __shfl_xor(ls, 2);
            float m = mem1[b * NHID + neuron];
            float sp_prev = (float)((lds_mask[b * 64 + wv] >> bitbase) & 1u);
            float mn = m * al + (1.f - al) * ls - VTH * sp_prev;
            bool spk = (mn - VTH) > 0.f;
            if ((r_l & 3) == 0) mem1[b * NHID + neuron] = mn;
            unsigned long long bal = __ballot(spk && ((r_l & 3) == 0));
            if (r_l == 0) {
                int base = (bg & 3) << 4;
                uint32_t nib = (uint32_t)((bal >> base) & 1ull) |
                               ((uint32_t)((bal >> (base + 4)) & 1ull) << 1) |
                               ((uint32_t)((bal >> (base + 8)) & 1ull) << 2) |
                               ((uint32_t)((bal >> (base + 12)) & 1ull) << 3);
                ((uint8_t*)spkg_next)[b * 256 + blk] = (uint8_t)nib;
            }
        }
    }

    // ---------- phase 2 (for step t-1): layer 2 + log_softmax ----------
    if (t > 0 && blk < 8) {
        int b = (blk << 4) + (tid >> 5);
        int o = tid & 31;
        const uint32_t* mw = &lds_mask[b * 64];
        float d2 = 0.f;
        for (int w = 0; w < 64; ++w) {
            uint32_t bits = mw[w];
            while (bits) {
                int p = __builtin_ctz(bits);
                bits &= bits - 1;
                int n = (w << 4) + ((p >> 3) << 2) + (p & 7);
                d2 += W2T[(n << 5) + o];
            }
        }
        float a2 = (o < NOUT) ? alpha2[o] : 0.f;
        d2 += (o < NOUT) ? b2[o] : 0.f;
        float m2 = (o < NOUT) ? mem2[b * NOUT + o] : 0.f;
        float s2 = (o < NOUT) ? spk2[b * NOUT + o] : 0.f;
        float m2n = m2 * a2 + (1.f - a2) * d2 - VTH * s2;
        if (o < NOUT) {
            mem2[b * NOUT + o] = m2n;
            spk2[b * NOUT + o] = ((m2n - VTH) > 0.f) ? 1.f : 0.f;
        }
        float v = (o < NOUT) ? m2n : -3.4e38f;
#pragma unroll
        for (int off = 16; off >= 1; off >>= 1) v = fmaxf(v, __shfl_xor(v, off, 32));
        float e = (o < NOUT) ? expf(m2n - v) : 0.f;
        float s = e;
#pragma unroll
        for (int off = 16; off >= 1; off >>= 1) s += __shfl_xor(s, off, 32);
        if (o < NOUT) out[((size_t)b * NOUT + o) * TSTEPS + (t - 1)] = (m2n - v) - logf(s);
    }
}

// ---------------- host ----------------

extern "C" void kernel_launch(void* const* d_in, const int* in_sizes, int n_in,
                              void* d_out, int out_size, void* d_ws, size_t ws_size,
                              hipStream_t stream) {
    const float* x      = (const float*)d_in[0];
    const float* W1     = (const float*)d_in[1];
    const float* b1     = (const float*)d_in[2];
    const float* tau_m1 = (const float*)d_in[3];
    const float* tau_n  = (const float*)d_in[4];
    const float* W2     = (const float*)d_in[5];
    const float* b2     = (const float*)d_in[6];
    const float* tau_m2 = (const float*)d_in[7];
    const float* mem1_0 = (const float*)d_in[8];
    const float* mem2_0 = (const float*)d_in[9];
    const int*   mask   = (const int*)d_in[10];
    float* out = (float*)d_out;

    float* ws = (float*)d_ws;
    size_t F = 0;
    float* alpha1 = ws + F; F += 1024;
    float* beta   = ws + F; F += 4096;
    float* alpha2 = ws + F; F += 32;
    float* mem1   = ws + F; F += BATCH * NHID;
    float* mem2   = ws + F; F += BATCH * NOUT;
    float* spk2   = ws + F; F += BATCH * NOUT;
    float* d_inp  = ws + F; F += BATCH * NR;
    float* W1xT   = ws + F; F += (size_t)NIN * NR;
    float* W1hTb  = ws + F; F += (size_t)256 * 16384;
    float* W2T    = ws + F; F += NHID * 32;
    uint32_t* spkg = (uint32_t*)(ws + F); F += 2 * BATCH * 64;
    float* ffx = ws + F;

    size_t ws_f = ws_size / 4;
    size_t avail = (ws_f > F) ? (ws_f - F) : 0;
    size_t per_t = (size_t)BATCH * NR;          // 524288 floats per timestep
    int Tc = (int)(avail / per_t);
    if (Tc < 1) Tc = 1;
    if (Tc > TSTEPS) Tc = TSTEPS;

    hipLaunchKernelGGL(setup_small, dim3(128), dim3(256), 0, stream,
                       tau_m1, tau_n, tau_m2, W2, alpha1, beta, alpha2, W2T);
    hipLaunchKernelGGL(setup_weights, dim3(2048), dim3(256), 0, stream, W1, mask, W1xT, W1hTb);
    hipLaunchKernelGGL(init_state, dim3(2048), dim3(256), 0, stream,
                       mem1_0, mem2_0, mem1, mem2, spk2, d_inp, spkg);

    int chunk_start = 0;
    while (chunk_start < TSTEPS) {
        int tc = TSTEPS - chunk_start;
        if (tc > Tc) tc = Tc;
        hipLaunchKernelGGL(ffx_gemm, dim3(tc, 32), dim3(256), 0, stream,
                           x, W1xT, b1, ffx, chunk_start, tc);
        for (int dt = 0; dt < tc; ++dt) {
            int tt = chunk_start + dt;
            const uint32_t* prev = spkg + (size_t)((tt + 1) & 1) * (BATCH * 64);
            uint32_t* next = spkg + (size_t)(tt & 1) * (BATCH * 64);
            hipLaunchKernelGGL(step_kernel, dim3(256), dim3(512), 0, stream,
                               alpha1, beta, alpha2, mem1, mem2, spk2, d_inp, W1hTb, W2T,
                               ffx, b2, out, prev, next, tt, dt, tc);
        }
        chunk_start += tc;
    }
    // final phase-2 (t = 249 outputs)
    {
        const uint32_t* prev = spkg + (size_t)((TSTEPS + 1) & 1) * (BATCH * 64);
        uint32_t* next = spkg + (size_t)(TSTEPS & 1) * (BATCH * 64);
        hipLaunchKernelGGL(step_kernel, dim3(8), dim3(512), 0, stream,
                           alpha1, beta, alpha2, mem1, mem2, spk2, d_inp, W1hTb, W2T,
                           ffx, b2, out, prev, next, TSTEPS, 0, 1);
    }
}